// Round 10
// baseline (434.252 us; speedup 1.0000x reference)
//
#include <hip/hip_runtime.h>

// Problem constants
#define B_    16
#define N1_   32
#define NL_   256
#define DM_   16
#define DOUT_ 16

#define NBN   (B_ * N1_)                  // 512 blocks
#define PROJ_ELEMS (NBN * NL_ * DOUT_)    // 2097152

// Flat LDS layout (float offsets), total 17408 floats = 69.6 KB -> 2 blocks/CU.
//   [0,1024)      weights Wq|Wk|Wv|Wo
//   [1024,5120)   QP (swizzled [256][16]) -- dead after Qp->regs; aliased by AT
//   [5120,9216)   ATX (AT rows 128..255; AT = [1024,9216) contiguous)
//   [9216,13312)  KP [256][16]            -- aliased by EMBA [128][17] in epilogue
//   [13312,17408) VP [256][16]            -- aliased by EMBB [128][17] in epilogue
#define WQ_OFF   0
#define WK_OFF   256
#define WV_OFF   512
#define WO_OFF   768
#define QP_OFF   1024
#define KP_OFF   9216
#define VP_OFF   13312
#define LDS_FLOATS 17408

// QP swizzle: row-major [256][16], bank-spread via (c+row)&15  (2-way, free)
#define QPA(row, c)  (QP_OFF + (row)*16 + (((c) + (row)) & 15))
// AT swizzle: [256][32] over the QP+ATX region, conflict-free via col^(row&31)
#define ATA(row, col) (QP_OFF + (row)*32 + ((col) ^ ((row) & 31)))

__global__ __launch_bounds__(512, 4)
void mha_relu_kernel(const float* __restrict__ Q,
                     const float* __restrict__ K,
                     const float* __restrict__ V,
                     const float* __restrict__ Wq,
                     const float* __restrict__ Wk,
                     const float* __restrict__ Wv,
                     const float* __restrict__ Wo,
                     float* __restrict__ proj_out,
                     float* __restrict__ attn_out)
{
    __shared__ float lds[LDS_FLOATS];

    const int tid = threadIdx.x;          // 0..511
    const int bn  = blockIdx.x;
    const int w   = tid >> 6;             // wave 0..7
    const int l   = tid & 63;
    const int wr  = w >> 2;               // row half 0/1
    const int wz  = w & 3;                // col slot 0..3

    // ---- weights -> LDS ----
    if (tid < 256) { lds[WQ_OFF + tid] = Wq[tid]; lds[WV_OFF + tid] = Wv[tid]; }
    else { lds[WK_OFF + tid - 256] = Wk[tid - 256]; lds[WO_OFF + tid - 256] = Wo[tid - 256]; }
    __syncthreads();

    const size_t inoff = (size_t)bn * NL_ * DM_;

    // ---- projections: pass1 Q|K (512 threads), pass2 V (256 threads) ----
    {
        float rowbuf[16], acc[16];
        const int r = tid & 255;
        {
            const float* src   = (tid < 256) ? (Q + inoff + (size_t)r * DM_)
                                             : (K + inoff + (size_t)r * DM_);
            const int    woff  = (tid < 256) ? WQ_OFF : WK_OFF;
            const float4* p = (const float4*)src;
            #pragma unroll
            for (int i = 0; i < 4; ++i) {
                float4 t4 = p[i];
                rowbuf[4*i+0] = t4.x; rowbuf[4*i+1] = t4.y;
                rowbuf[4*i+2] = t4.z; rowbuf[4*i+3] = t4.w;
            }
            #pragma unroll
            for (int c = 0; c < 16; ++c) acc[c] = 0.f;
            #pragma unroll
            for (int i = 0; i < 16; ++i) {
                const float xi = rowbuf[i];
                #pragma unroll
                for (int c = 0; c < 16; ++c) acc[c] += xi * lds[woff + i*16 + c];
            }
            if (tid < 256) {
                #pragma unroll
                for (int c = 0; c < 16; ++c) lds[QPA(r, c)] = acc[c];
            } else {
                #pragma unroll
                for (int c = 0; c < 16; ++c) lds[KP_OFF + r*16 + c] = acc[c];
            }
        }
        if (tid < 256) {
            const float4* p = (const float4*)(V + inoff + (size_t)r * DM_);
            #pragma unroll
            for (int i = 0; i < 4; ++i) {
                float4 t4 = p[i];
                rowbuf[4*i+0] = t4.x; rowbuf[4*i+1] = t4.y;
                rowbuf[4*i+2] = t4.z; rowbuf[4*i+3] = t4.w;
            }
            #pragma unroll
            for (int c = 0; c < 16; ++c) acc[c] = 0.f;
            #pragma unroll
            for (int i = 0; i < 16; ++i) {
                const float vi = rowbuf[i];
                #pragma unroll
                for (int c = 0; c < 16; ++c) acc[c] += vi * lds[WV_OFF + i*16 + c];
            }
            #pragma unroll
            for (int c = 0; c < 16; ++c) lds[VP_OFF + r*16 + c] = acc[c];
        }
    }
    __syncthreads();

    // ---- this lane's 2 Qp rows -> registers (swizzled reads: 2-way, free) ----
    float Qp[2][16];
    #pragma unroll
    for (int jj = 0; jj < 2; ++jj) {
        const int row = 128*wr + 64*jj + l;
        #pragma unroll
        for (int c = 0; c < 16; ++c) Qp[jj][c] = lds[QPA(row, c)];
    }

    float emb[2][16];
    #pragma unroll
    for (int jj = 0; jj < 2; ++jj)
        #pragma unroll
        for (int c = 0; c < 16; ++c) emb[jj][c] = 0.f;

    float* aout = attn_out + (size_t)bn * NL_ * NL_;

    // ---- main loop: 8 col-tiles of 32; wave w owns cols 8wz..8wz+8 ----
    #pragma unroll 1
    for (int t = 0; t < 8; ++t) {
        float atr[2][8];
        #pragma unroll
        for (int e = 0; e < 8; ++e) {
            const int z = 32*t + 8*wz + e;
            float s0a = 0.f, s0b = 0.f, s1a = 0.f, s1b = 0.f;
            {
                const float4* kp = (const float4*)&lds[KP_OFF + z*16];
                float4 x;
                x = kp[0];
                s0a += Qp[0][0]*x.x + Qp[0][1]*x.y + Qp[0][2]*x.z + Qp[0][3]*x.w;
                s1a += Qp[1][0]*x.x + Qp[1][1]*x.y + Qp[1][2]*x.z + Qp[1][3]*x.w;
                x = kp[1];
                s0a += Qp[0][4]*x.x + Qp[0][5]*x.y + Qp[0][6]*x.z + Qp[0][7]*x.w;
                s1a += Qp[1][4]*x.x + Qp[1][5]*x.y + Qp[1][6]*x.z + Qp[1][7]*x.w;
                x = kp[2];
                s0b += Qp[0][8]*x.x + Qp[0][9]*x.y + Qp[0][10]*x.z + Qp[0][11]*x.w;
                s1b += Qp[1][8]*x.x + Qp[1][9]*x.y + Qp[1][10]*x.z + Qp[1][11]*x.w;
                x = kp[3];
                s0b += Qp[0][12]*x.x + Qp[0][13]*x.y + Qp[0][14]*x.z + Qp[0][15]*x.w;
                s1b += Qp[1][12]*x.x + Qp[1][13]*x.y + Qp[1][14]*x.z + Qp[1][15]*x.w;
            }
            s0a = fmaxf(s0a, 0.f); s0b = fmaxf(s0b, 0.f);
            s1a = fmaxf(s1a, 0.f); s1b = fmaxf(s1b, 0.f);
            atr[0][e] = 0.5f * (s0a + s0b);
            atr[1][e] = 0.5f * (s1a + s1b);
            {
                const float4* vp = (const float4*)&lds[VP_OFF + z*16];
                float4 x;
                x = vp[0];
                emb[0][0]  += s0a*x.x; emb[0][1]  += s0a*x.y; emb[0][2]  += s0a*x.z; emb[0][3]  += s0a*x.w;
                emb[1][0]  += s1a*x.x; emb[1][1]  += s1a*x.y; emb[1][2]  += s1a*x.z; emb[1][3]  += s1a*x.w;
                x = vp[1];
                emb[0][4]  += s0a*x.x; emb[0][5]  += s0a*x.y; emb[0][6]  += s0a*x.z; emb[0][7]  += s0a*x.w;
                emb[1][4]  += s1a*x.x; emb[1][5]  += s1a*x.y; emb[1][6]  += s1a*x.z; emb[1][7]  += s1a*x.w;
                x = vp[2];
                emb[0][8]  += s0b*x.x; emb[0][9]  += s0b*x.y; emb[0][10] += s0b*x.z; emb[0][11] += s0b*x.w;
                emb[1][8]  += s1b*x.x; emb[1][9]  += s1b*x.y; emb[1][10] += s1b*x.z; emb[1][11] += s1b*x.w;
                x = vp[3];
                emb[0][12] += s0b*x.x; emb[0][13] += s0b*x.y; emb[0][14] += s0b*x.z; emb[0][15] += s0b*x.w;
                emb[1][12] += s1b*x.x; emb[1][13] += s1b*x.y; emb[1][14] += s1b*x.z; emb[1][15] += s1b*x.w;
            }
        }
        __syncthreads();                  // prev tile's AT reads (and Qp loads) done
        #pragma unroll
        for (int jj = 0; jj < 2; ++jj)
            #pragma unroll
            for (int e = 0; e < 8; ++e)
                lds[ATA(128*wr + 64*jj + l, 8*wz + e)] = atr[jj][e];
        __syncthreads();
        // cooperative store: per wave-instr 2 rows x 32 cols = full 128-B lines
        #pragma unroll
        for (int i = 0; i < 16; ++i) {
            const int idx = i*512 + tid;  // over [256 rows][32 cols]
            const int row = idx >> 5;
            const int col = idx & 31;
            aout[(size_t)row * NL_ + 32*t + col] = lds[ATA(row, col)];
        }
    }

    // ---- emb reduction into dead KP (half 0) / VP (half 1), stride 17 ----
    __syncthreads();
    {
        const int base = (wr == 0) ? KP_OFF : VP_OFF;
        if (wz == 0) {
            #pragma unroll
            for (int jj = 0; jj < 2; ++jj)
                #pragma unroll
                for (int c = 0; c < 16; ++c)
                    lds[base + (64*jj + l)*17 + c] = emb[jj][c];
        }
        __syncthreads();
        if (wz == 1) {
            #pragma unroll
            for (int jj = 0; jj < 2; ++jj)
                #pragma unroll
                for (int c = 0; c < 16; ++c)
                    lds[base + (64*jj + l)*17 + c] += emb[jj][c];
        }
        __syncthreads();
        if (wz == 2) {
            #pragma unroll
            for (int jj = 0; jj < 2; ++jj)
                #pragma unroll
                for (int c = 0; c < 16; ++c)
                    lds[base + (64*jj + l)*17 + c] += emb[jj][c];
        }
        __syncthreads();
        if (wz == 3) {
            #pragma unroll
            for (int jj = 0; jj < 2; ++jj)
                #pragma unroll
                for (int c = 0; c < 16; ++c)
                    lds[base + (64*jj + l)*17 + c] += emb[jj][c];
        }
    }
    __syncthreads();

    // ---- output projection: threads 0..255, thread t owns row t ----
    if (tid < 256) {
        const int base = (tid < 128) ? KP_OFF : VP_OFF;
        const int r    = tid & 127;
        float e[16];
        #pragma unroll
        for (int c = 0; c < 16; ++c) e[c] = lds[base + r*17 + c];

        float pr[16];
        #pragma unroll
        for (int o = 0; o < 16; ++o) pr[o] = 0.f;
        #pragma unroll
        for (int a = 0; a < 2; ++a) {
            #pragma unroll
            for (int m = 0; m < 8; ++m) {
                const float ev = e[a*8 + m];
                #pragma unroll
                for (int o = 0; o < 16; ++o) pr[o] += ev * lds[WO_OFF + m*32 + a*16 + o];
            }
        }
        float4* po = (float4*)(proj_out + (size_t)bn * NL_ * DOUT_ + (size_t)tid * DOUT_);
        po[0] = make_float4(pr[0],  pr[1],  pr[2],  pr[3]);
        po[1] = make_float4(pr[4],  pr[5],  pr[6],  pr[7]);
        po[2] = make_float4(pr[8],  pr[9],  pr[10], pr[11]);
        po[3] = make_float4(pr[12], pr[13], pr[14], pr[15]);
    }
}

extern "C" void kernel_launch(void* const* d_in, const int* in_sizes, int n_in,
                              void* d_out, int out_size, void* d_ws, size_t ws_size,
                              hipStream_t stream) {
    const float* Q  = (const float*)d_in[0];
    const float* K  = (const float*)d_in[1];
    const float* V  = (const float*)d_in[2];
    const float* Wq = (const float*)d_in[3];
    const float* Wk = (const float*)d_in[4];
    const float* Wv = (const float*)d_in[5];
    const float* Wo = (const float*)d_in[6];

    float* proj = (float*)d_out;
    float* attn = (float*)d_out + PROJ_ELEMS;

    mha_relu_kernel<<<NBN, 512, 0, stream>>>(Q, K, V, Wq, Wk, Wv, Wo, proj, attn);
}

// Round 11
// 79.247 us; speedup vs baseline: 5.4797x; 5.4797x over previous
//
#include <hip/hip_runtime.h>

// Problem constants
#define B_    16
#define N1_   32
#define NL_   256
#define DM_   16
#define DOUT_ 16

#define NBN   (B_ * N1_)                  // 512 blocks
#define PROJ_ELEMS (NBN * NL_ * DOUT_)    // 2097152

// Flat LDS layout (float offsets), total 17408 floats = 69.6 KB -> 2 blocks/CU.
//   [0,1024)      weights Wq|Wk|Wv|Wo
//   [1024,5120)   QP (swizzled [256][16]) -- dead after Qp->regs; aliased by AT
//   [5120,9216)   ATX (AT rows 128..255; AT = [1024,9216) contiguous)
//   [9216,13312)  KP [256][16]            -- aliased by EMBA [128][17] in epilogue
//   [13312,17408) VP [256][16]            -- aliased by EMBB [128][17] in epilogue
#define WQ_OFF   0
#define WK_OFF   256
#define WV_OFF   512
#define WO_OFF   768
#define QP_OFF   1024
#define KP_OFF   9216
#define VP_OFF   13312
#define LDS_FLOATS 17408

// QP swizzle: row-major [256][16], bank-spread via (c+row)&15  (2-way, free)
#define QPA(row, c)  (QP_OFF + (row)*16 + (((c) + (row)) & 15))
// AT swizzle: [256][32] over the QP+ATX region, conflict-free via col^(row&31)
#define ATA(row, col) (QP_OFF + (row)*32 + ((col) ^ ((row) & 31)))

// NOTE launch bounds: (512, 2) => compiler allocates 128 VGPRs, no spill
// (measured round 9). (512, 4) => compiler caps at 64 VGPRs and spills ~1.7 GB
// to scratch (measured round 10). Occupancy of 2 blocks/CU comes from
// LDS = 69.6 KB <= 80 KB, not from the bound.
__global__ __launch_bounds__(512, 2)
void mha_relu_kernel(const float* __restrict__ Q,
                     const float* __restrict__ K,
                     const float* __restrict__ V,
                     const float* __restrict__ Wq,
                     const float* __restrict__ Wk,
                     const float* __restrict__ Wv,
                     const float* __restrict__ Wo,
                     float* __restrict__ proj_out,
                     float* __restrict__ attn_out)
{
    __shared__ float lds[LDS_FLOATS];

    const int tid = threadIdx.x;          // 0..511
    const int bn  = blockIdx.x;
    const int w   = tid >> 6;             // wave 0..7
    const int l   = tid & 63;
    const int wr  = w >> 2;               // row half 0/1
    const int wz  = w & 3;                // col slot 0..3

    // ---- weights -> LDS ----
    if (tid < 256) { lds[WQ_OFF + tid] = Wq[tid]; lds[WV_OFF + tid] = Wv[tid]; }
    else { lds[WK_OFF + tid - 256] = Wk[tid - 256]; lds[WO_OFF + tid - 256] = Wo[tid - 256]; }
    __syncthreads();

    const size_t inoff = (size_t)bn * NL_ * DM_;

    // ---- projections: pass1 Q|K (512 threads), pass2 V (256 threads) ----
    {
        float rowbuf[16], acc[16];
        const int r = tid & 255;
        {
            const float* src   = (tid < 256) ? (Q + inoff + (size_t)r * DM_)
                                             : (K + inoff + (size_t)r * DM_);
            const int    woff  = (tid < 256) ? WQ_OFF : WK_OFF;
            const float4* p = (const float4*)src;
            #pragma unroll
            for (int i = 0; i < 4; ++i) {
                float4 t4 = p[i];
                rowbuf[4*i+0] = t4.x; rowbuf[4*i+1] = t4.y;
                rowbuf[4*i+2] = t4.z; rowbuf[4*i+3] = t4.w;
            }
            #pragma unroll
            for (int c = 0; c < 16; ++c) acc[c] = 0.f;
            #pragma unroll
            for (int i = 0; i < 16; ++i) {
                const float xi = rowbuf[i];
                #pragma unroll
                for (int c = 0; c < 16; ++c) acc[c] += xi * lds[woff + i*16 + c];
            }
            if (tid < 256) {
                #pragma unroll
                for (int c = 0; c < 16; ++c) lds[QPA(r, c)] = acc[c];
            } else {
                #pragma unroll
                for (int c = 0; c < 16; ++c) lds[KP_OFF + r*16 + c] = acc[c];
            }
        }
        if (tid < 256) {
            const float4* p = (const float4*)(V + inoff + (size_t)r * DM_);
            #pragma unroll
            for (int i = 0; i < 4; ++i) {
                float4 t4 = p[i];
                rowbuf[4*i+0] = t4.x; rowbuf[4*i+1] = t4.y;
                rowbuf[4*i+2] = t4.z; rowbuf[4*i+3] = t4.w;
            }
            #pragma unroll
            for (int c = 0; c < 16; ++c) acc[c] = 0.f;
            #pragma unroll
            for (int i = 0; i < 16; ++i) {
                const float vi = rowbuf[i];
                #pragma unroll
                for (int c = 0; c < 16; ++c) acc[c] += vi * lds[WV_OFF + i*16 + c];
            }
            #pragma unroll
            for (int c = 0; c < 16; ++c) lds[VP_OFF + r*16 + c] = acc[c];
        }
    }
    __syncthreads();

    // ---- this lane's 2 Qp rows -> registers (swizzled reads: 2-way, free) ----
    float Qp[2][16];
    #pragma unroll
    for (int jj = 0; jj < 2; ++jj) {
        const int row = 128*wr + 64*jj + l;
        #pragma unroll
        for (int c = 0; c < 16; ++c) Qp[jj][c] = lds[QPA(row, c)];
    }

    float emb[2][16];
    #pragma unroll
    for (int jj = 0; jj < 2; ++jj)
        #pragma unroll
        for (int c = 0; c < 16; ++c) emb[jj][c] = 0.f;

    float* aout = attn_out + (size_t)bn * NL_ * NL_;

    // ---- main loop: 8 col-tiles of 32; wave w owns cols 8wz..8wz+8 ----
    #pragma unroll 1
    for (int t = 0; t < 8; ++t) {
        float atr[2][8];
        #pragma unroll
        for (int e = 0; e < 8; ++e) {
            const int z = 32*t + 8*wz + e;
            float s0a = 0.f, s0b = 0.f, s1a = 0.f, s1b = 0.f;
            {
                const float4* kp = (const float4*)&lds[KP_OFF + z*16];
                float4 x;
                x = kp[0];
                s0a += Qp[0][0]*x.x + Qp[0][1]*x.y + Qp[0][2]*x.z + Qp[0][3]*x.w;
                s1a += Qp[1][0]*x.x + Qp[1][1]*x.y + Qp[1][2]*x.z + Qp[1][3]*x.w;
                x = kp[1];
                s0a += Qp[0][4]*x.x + Qp[0][5]*x.y + Qp[0][6]*x.z + Qp[0][7]*x.w;
                s1a += Qp[1][4]*x.x + Qp[1][5]*x.y + Qp[1][6]*x.z + Qp[1][7]*x.w;
                x = kp[2];
                s0b += Qp[0][8]*x.x + Qp[0][9]*x.y + Qp[0][10]*x.z + Qp[0][11]*x.w;
                s1b += Qp[1][8]*x.x + Qp[1][9]*x.y + Qp[1][10]*x.z + Qp[1][11]*x.w;
                x = kp[3];
                s0b += Qp[0][12]*x.x + Qp[0][13]*x.y + Qp[0][14]*x.z + Qp[0][15]*x.w;
                s1b += Qp[1][12]*x.x + Qp[1][13]*x.y + Qp[1][14]*x.z + Qp[1][15]*x.w;
            }
            s0a = fmaxf(s0a, 0.f); s0b = fmaxf(s0b, 0.f);
            s1a = fmaxf(s1a, 0.f); s1b = fmaxf(s1b, 0.f);
            atr[0][e] = 0.5f * (s0a + s0b);
            atr[1][e] = 0.5f * (s1a + s1b);
            {
                const float4* vp = (const float4*)&lds[VP_OFF + z*16];
                float4 x;
                x = vp[0];
                emb[0][0]  += s0a*x.x; emb[0][1]  += s0a*x.y; emb[0][2]  += s0a*x.z; emb[0][3]  += s0a*x.w;
                emb[1][0]  += s1a*x.x; emb[1][1]  += s1a*x.y; emb[1][2]  += s1a*x.z; emb[1][3]  += s1a*x.w;
                x = vp[1];
                emb[0][4]  += s0a*x.x; emb[0][5]  += s0a*x.y; emb[0][6]  += s0a*x.z; emb[0][7]  += s0a*x.w;
                emb[1][4]  += s1a*x.x; emb[1][5]  += s1a*x.y; emb[1][6]  += s1a*x.z; emb[1][7]  += s1a*x.w;
                x = vp[2];
                emb[0][8]  += s0b*x.x; emb[0][9]  += s0b*x.y; emb[0][10] += s0b*x.z; emb[0][11] += s0b*x.w;
                emb[1][8]  += s1b*x.x; emb[1][9]  += s1b*x.y; emb[1][10] += s1b*x.z; emb[1][11] += s1b*x.w;
                x = vp[3];
                emb[0][12] += s0b*x.x; emb[0][13] += s0b*x.y; emb[0][14] += s0b*x.z; emb[0][15] += s0b*x.w;
                emb[1][12] += s1b*x.x; emb[1][13] += s1b*x.y; emb[1][14] += s1b*x.z; emb[1][15] += s1b*x.w;
            }
        }
        __syncthreads();                  // prev tile's AT reads (and Qp loads) done
        #pragma unroll
        for (int jj = 0; jj < 2; ++jj)
            #pragma unroll
            for (int e = 0; e < 8; ++e)
                lds[ATA(128*wr + 64*jj + l, 8*wz + e)] = atr[jj][e];
        __syncthreads();
        // cooperative store: per wave-instr 2 rows x 32 cols = full 128-B lines
        #pragma unroll
        for (int i = 0; i < 16; ++i) {
            const int idx = i*512 + tid;  // over [256 rows][32 cols]
            const int row = idx >> 5;
            const int col = idx & 31;
            aout[(size_t)row * NL_ + 32*t + col] = lds[ATA(row, col)];
        }
    }

    // ---- emb reduction into dead KP (half 0) / VP (half 1), stride 17 ----
    __syncthreads();
    {
        const int base = (wr == 0) ? KP_OFF : VP_OFF;
        if (wz == 0) {
            #pragma unroll
            for (int jj = 0; jj < 2; ++jj)
                #pragma unroll
                for (int c = 0; c < 16; ++c)
                    lds[base + (64*jj + l)*17 + c] = emb[jj][c];
        }
        __syncthreads();
        if (wz == 1) {
            #pragma unroll
            for (int jj = 0; jj < 2; ++jj)
                #pragma unroll
                for (int c = 0; c < 16; ++c)
                    lds[base + (64*jj + l)*17 + c] += emb[jj][c];
        }
        __syncthreads();
        if (wz == 2) {
            #pragma unroll
            for (int jj = 0; jj < 2; ++jj)
                #pragma unroll
                for (int c = 0; c < 16; ++c)
                    lds[base + (64*jj + l)*17 + c] += emb[jj][c];
        }
        __syncthreads();
        if (wz == 3) {
            #pragma unroll
            for (int jj = 0; jj < 2; ++jj)
                #pragma unroll
                for (int c = 0; c < 16; ++c)
                    lds[base + (64*jj + l)*17 + c] += emb[jj][c];
        }
    }
    __syncthreads();

    // ---- output projection: threads 0..255, thread t owns row t ----
    if (tid < 256) {
        const int base = (tid < 128) ? KP_OFF : VP_OFF;
        const int r    = tid & 127;
        float e[16];
        #pragma unroll
        for (int c = 0; c < 16; ++c) e[c] = lds[base + r*17 + c];

        float pr[16];
        #pragma unroll
        for (int o = 0; o < 16; ++o) pr[o] = 0.f;
        #pragma unroll
        for (int a = 0; a < 2; ++a) {
            #pragma unroll
            for (int m = 0; m < 8; ++m) {
                const float ev = e[a*8 + m];
                #pragma unroll
                for (int o = 0; o < 16; ++o) pr[o] += ev * lds[WO_OFF + m*32 + a*16 + o];
            }
        }
        float4* po = (float4*)(proj_out + (size_t)bn * NL_ * DOUT_ + (size_t)tid * DOUT_);
        po[0] = make_float4(pr[0],  pr[1],  pr[2],  pr[3]);
        po[1] = make_float4(pr[4],  pr[5],  pr[6],  pr[7]);
        po[2] = make_float4(pr[8],  pr[9],  pr[10], pr[11]);
        po[3] = make_float4(pr[12], pr[13], pr[14], pr[15]);
    }
}

extern "C" void kernel_launch(void* const* d_in, const int* in_sizes, int n_in,
                              void* d_out, int out_size, void* d_ws, size_t ws_size,
                              hipStream_t stream) {
    const float* Q  = (const float*)d_in[0];
    const float* K  = (const float*)d_in[1];
    const float* V  = (const float*)d_in[2];
    const float* Wq = (const float*)d_in[3];
    const float* Wk = (const float*)d_in[4];
    const float* Wv = (const float*)d_in[5];
    const float* Wo = (const float*)d_in[6];

    float* proj = (float*)d_out;
    float* attn = (float*)d_out + PROJ_ELEMS;

    mha_relu_kernel<<<NBN, 512, 0, stream>>>(Q, K, V, Wq, Wk, Wv, Wo, proj, attn);
}